// Round 10
// baseline (104.089 us; speedup 1.0000x reference)
//
#include <hip/hip_runtime.h>
#include <hip/hip_fp16.h>

#define NQ 4096
#define NH 8
#define ND 32
#define NK 30720   // 16384+8192+4096+2048
#define LDSS 33    // padded LDS row stride (conflict-free)

// ---- Pre-pass: value fp32 -> fp16 into workspace (halves gather traffic) ----
__global__ __launch_bounds__(256) void cvt_kernel(const float* __restrict__ v,
                                                  uint4* __restrict__ o, int n8) {
    int i = blockIdx.x * blockDim.x + threadIdx.x;
    const float4* __restrict__ v4 = (const float4*)v;
    for (; i < n8; i += gridDim.x * blockDim.x) {
        const float4 f0 = v4[2 * i];
        const float4 f1 = v4[2 * i + 1];
        __half2 h0 = __floats2half2_rn(f0.x, f0.y);
        __half2 h1 = __floats2half2_rn(f0.z, f0.w);
        __half2 h2 = __floats2half2_rn(f1.x, f1.y);
        __half2 h3 = __floats2half2_rn(f1.z, f1.w);
        uint4 u;
        u.x = *reinterpret_cast<unsigned*>(&h0);
        u.y = *reinterpret_cast<unsigned*>(&h1);
        u.z = *reinterpret_cast<unsigned*>(&h2);
        u.w = *reinterpret_cast<unsigned*>(&h3);
        o[i] = u;
    }
}

// Partition (R5 winner): 8 groups = (batch, h-half) -> one per XCD.
// NEW: temporal level-split. Per-XCD fp16 gather footprint by level:
// L0 = 4.0 MB, L1 = 2.0 MB, L2 = 1.0 MB, L3 = 0.5 MB; total 7.86 MB = 2x the
// 4 MB XCD-L2 (this, not issue depth, was the R5 limiter -- R3/4/6/8/9 all
// failed to beat the plain loop). Kernel A (taps [0,8) = L0, 4.0 MB) writes
// out; kernel B (taps [8,32) = L1-3, 3.67 MB) accumulates into out. Each
// kernel's working set ~fits its XCD-L2 -> near-compulsory HBM traffic.
// Block = 8 queries x 4 heads; plain load-consume loop (proven).
template <int J0, int J1, bool ACCUM, bool FP16>
__global__ __launch_bounds__(256, 8) void spd_kernel(
    const float* __restrict__ value,   // (bs, NK, H, D) fp32
    const __half* __restrict__ vh,     // same, fp16 (workspace), if FP16
    const float* __restrict__ loc,     // (bs, NQ, H, LV, P, 1)
    const float* __restrict__ wts,     // (bs, NQ, H, LV, P)
    float* __restrict__ out)           // (bs, NQ, H*D)
{
    constexpr int NROWS = J1 - J0;
    const int tid = threadIdx.x;
    const int g8 = blockIdx.x & 7;     // XCD id = group = b*2 + hh
    const int w  = blockIdx.x >> 3;    // [0,512) within group
    const int b  = g8 >> 1;
    const int hh = g8 & 1;             // which half of the 8 heads
    const int q0 = w << 3;             // first of 8 queries

    __shared__ uint2 s_d[NROWS * LDSS];  // [row-J0][col=q*4+h4]

    // ---- Phase 1: descriptors for 8 queries x 4 heads x NROWS taps ----
    const size_t base = (size_t)(b * NQ + q0) * 256 + hh * 128;
    #pragma unroll
    for (int e = 0; e < (NROWS * 32) / 256; ++e) {
        const int idx = (e << 8) | tid;
        const int row = J0 + (idx >> 5);    // l*8+p
        const int col = idx & 31;           // q*4+h4
        const size_t gidx = base + (size_t)(col >> 2) * 256 + ((col & 3) << 5) + row;
        const float x_loc = loc[gidx];
        const float wq    = wts[gidx];

        const int l   = row >> 3;
        const int L   = 16384 >> l;
        const int off = 32768 - (32768 >> l); // 0,16384,24576,28672

        const float x  = x_loc * (float)L - 1.0f;
        const float xf = floorf(x);
        const float lx = x - xf;
        const float hx = 1.0f - lx;
        const int   xl = (int)xf;
        const int   xh = xl + 1;

        const bool ok1 = (xl >= 0) && (xl < L);
        const bool ok2 = (xh >= 0) && (xh < L);
        int c1 = xl < 0 ? 0 : (xl > L - 1 ? L - 1 : xl);
        int c2 = xh < 0 ? 0 : (xh > L - 1 ? L - 1 : xh);
        const float w1 = ok1 ? wq * hx : 0.0f;
        const float w2 = ok2 ? wq * lx : 0.0f;

        __half2 wh = __floats2half2_rn(w1, w2);
        uint2 d;
        d.x = (unsigned)(off + c1) | ((unsigned)(off + c2) << 16);
        d.y = *reinterpret_cast<unsigned*>(&wh);
        s_d[(row - J0) * LDSS + col] = d;
    }
    __syncthreads();

    // ---- Phase 2: gather + accumulate (plain load-consume, R5 structure) ----
    const int cb = tid >> 3;                 // LDS col = q*4+h4 [0,32)
    const int h  = (hh << 2) | ((tid >> 3) & 3);
    const int d4 = tid & 7;
    const unsigned lane = (unsigned)((h << 3) | d4);  // slice within key row
    float4* __restrict__ o4 = (float4*)out;
    const size_t oidx = (size_t)(b * NQ + q0 + (tid >> 5)) * 64 + lane;

    float4 acc = make_float4(0.f, 0.f, 0.f, 0.f);
    if (ACCUM) acc = o4[oidx];

    if (FP16) {
        const uint2* __restrict__ vb2 =
            (const uint2*)(vh) + (size_t)b * (NK * 64);   // 64 uint2 per key
        #pragma unroll 8
        for (int j = 0; j < NROWS; ++j) {
            const uint2 d = s_d[j * LDSS + cb];
            const __half2 wh = *reinterpret_cast<const __half2*>(&d.y);
            const float w1 = __low2float(wh);
            const float w2 = __high2float(wh);
            const uint2 r1 = vb2[((d.x & 0xffffu) << 6) + lane];
            const uint2 r2 = vb2[((d.x >> 16) << 6) + lane];
            const float2 a0 = __half22float2(*(const __half2*)&r1.x);
            const float2 a1 = __half22float2(*(const __half2*)&r1.y);
            const float2 c0 = __half22float2(*(const __half2*)&r2.x);
            const float2 c1 = __half22float2(*(const __half2*)&r2.y);
            acc.x += w1 * a0.x + w2 * c0.x;
            acc.y += w1 * a0.y + w2 * c0.y;
            acc.z += w1 * a1.x + w2 * c1.x;
            acc.w += w1 * a1.y + w2 * c1.y;
        }
    } else {
        const float4* __restrict__ vb4 =
            (const float4*)(value) + (size_t)b * (NK * 64); // 64 float4 per key
        #pragma unroll 8
        for (int j = 0; j < NROWS; ++j) {
            const uint2 d = s_d[j * LDSS + cb];
            const __half2 wh = *reinterpret_cast<const __half2*>(&d.y);
            const float w1 = __low2float(wh);
            const float w2 = __high2float(wh);
            const float4 a = vb4[(size_t)((d.x & 0xffffu) << 6) + lane];
            const float4 c = vb4[(size_t)((d.x >> 16) << 6) + lane];
            acc.x += w1 * a.x + w2 * c.x;
            acc.y += w1 * a.y + w2 * c.y;
            acc.z += w1 * a.z + w2 * c.z;
            acc.w += w1 * a.w + w2 * c.w;
        }
    }

    o4[oidx] = acc;
}

extern "C" void kernel_launch(void* const* d_in, const int* in_sizes, int n_in,
                              void* d_out, int out_size, void* d_ws, size_t ws_size,
                              hipStream_t stream) {
    const float* value = (const float*)d_in[0];
    const float* loc   = (const float*)d_in[1];
    const float* wts   = (const float*)d_in[2];
    float* out = (float*)d_out;

    const int bs = 4;
    const int blocks = 8 * (NQ / 8);  // 8 groups x 512 = 4096
    const size_t need = (size_t)bs * NK * NH * ND * sizeof(__half);  // ~63 MB

    if (ws_size >= need) {
        const int n8 = bs * NK * NH * ND / 8;  // 8 floats per thread-iter
        cvt_kernel<<<2048, 256, 0, stream>>>(value, (uint4*)d_ws, n8);
        // A: level 0 (4.0 MB/XCD), overwrite out
        spd_kernel<0, 8, false, true><<<blocks, 256, 0, stream>>>(
            value, (const __half*)d_ws, loc, wts, out);
        // B: levels 1-3 (3.67 MB/XCD), accumulate into out
        spd_kernel<8, 32, true, true><<<blocks, 256, 0, stream>>>(
            value, (const __half*)d_ws, loc, wts, out);
    } else {
        spd_kernel<0, 32, false, false><<<blocks, 256, 0, stream>>>(
            value, nullptr, loc, wts, out);
    }
}

// Round 11
// 91.665 us; speedup vs baseline: 1.1355x; 1.1355x over previous
//
#include <hip/hip_runtime.h>
#include <hip/hip_fp16.h>

#define NQ 4096
#define NH 8
#define ND 32
#define NK 30720   // 16384+8192+4096+2048
#define LDSS 33    // padded LDS row stride (conflict-free)

// ---- Pre-pass: value (b,key,h,d) fp32 -> TRANSPOSED (b,h,key,d) fp16 ----
// Transpose makes key k / k+1 rows of one head adjacent 64B lines, so the
// interp pair is one contiguous 128B span (one load instr per tap downstream).
__global__ __launch_bounds__(256) void cvt_t_kernel(const float* __restrict__ v,
                                                    uint4* __restrict__ o) {
    const int bh = blockIdx.x / 480;            // 480 = NK*4/256 blocks per (b,h)
    const int kc = blockIdx.x - bh * 480;
    const int b  = bh >> 3, h = bh & 7;
    const int chunk = (kc << 8) | threadIdx.x;  // [0, NK*4) 16B-chunks
    const int key = chunk >> 2, qt = chunk & 3;
    const float4* __restrict__ v4 = (const float4*)v;
    const size_t ii = ((size_t)(b * NK + key) * 8 + h) * 8 + qt * 2;
    const float4 f0 = v4[ii];
    const float4 f1 = v4[ii + 1];
    __half2 h0 = __floats2half2_rn(f0.x, f0.y);
    __half2 h1 = __floats2half2_rn(f0.z, f0.w);
    __half2 h2 = __floats2half2_rn(f1.x, f1.y);
    __half2 h3 = __floats2half2_rn(f1.z, f1.w);
    uint4 u;
    u.x = *reinterpret_cast<unsigned*>(&h0);
    u.y = *reinterpret_cast<unsigned*>(&h1);
    u.z = *reinterpret_cast<unsigned*>(&h2);
    u.w = *reinterpret_cast<unsigned*>(&h3);
    o[(size_t)bh * (NK * 4) + chunk] = u;
}

// Partition (R5 winner): 8 groups = (batch, h-half) -> one per XCD.
// Block = 8 queries x 4 heads. Phase 1: R5's verbatim coalesced descriptor
// build; NEW encoding (base, wa, wb): out += wa*v[base] + wb*v[base+1].
// Phase 2: per tap, the 8 lanes of a (q,h) group issue ONE contiguous 128B
// span load covering rows base/base+1 (16 lines per wave-instruction = 2x R5);
// lanes 0-3 weight wa, lanes 4-7 weight wb; cross-lane (l ^ 4) sum deferred
// to a single epilogue shfl_xor. Plain load-consume loop (schedulers lost 6x).
template <bool FP16>
__global__ __launch_bounds__(256, 8) void spd_kernel(
    const float* __restrict__ value,   // (bs, NK, H, D) fp32 (fallback)
    const __half* __restrict__ vh,     // (bs, H, NK, D) fp16 (workspace)
    const float* __restrict__ loc,     // (bs, NQ, H, LV, P, 1)
    const float* __restrict__ wts,     // (bs, NQ, H, LV, P)
    float* __restrict__ out)           // (bs, NQ, H*D)
{
    const int tid = threadIdx.x;
    const int g8 = blockIdx.x & 7;     // XCD id = group = b*2 + hh
    const int w  = blockIdx.x >> 3;    // [0,512) within group
    const int b  = g8 >> 1;
    const int hh = g8 & 1;             // which half of the 8 heads
    const int q0 = w << 3;             // first of 8 queries

    __shared__ uint2 s_d[32 * LDSS];   // {base_key, half2(wa,wb)}

    // ---- Phase 1: descriptors (R5 verbatim mapping, new encoding) ----
    const size_t base = ((size_t)(b * NQ + q0) * 8 + hh * 4) * 32;
    #pragma unroll
    for (int e = 0; e < 4; ++e) {
        const int ent = (e << 8) | tid;    // q(3b)|h4(2b)|l(2b)|p(3b)
        const size_t gidx = base + (size_t)(ent >> 7) * 256 + (ent & 127);
        const float x_loc = loc[gidx];
        const float wq    = wts[gidx];

        const int l   = (ent >> 3) & 3;
        const int L   = 16384 >> l;
        const int off = 32768 - (32768 >> l); // 0,16384,24576,28672

        const float x  = x_loc * (float)L - 1.0f;
        const float xf = floorf(x);
        const float lx = x - xf;
        const float hx = 1.0f - lx;
        const int   xl = (int)xf;

        int   bse = 0;
        float wa = 0.0f, wb = 0.0f;
        if (xl >= 0 && xl < L) {
            bse = xl;
            wa  = wq * hx;
            wb  = (xl + 1 < L) ? wq * lx : 0.0f;
        } else if (xl == -1) {           // only xh=0 in range
            bse = 0;
            wa  = wq * lx;
            wb  = 0.0f;
        }

        const int li = (ent & 31) * LDSS + (ent >> 5);  // row=lp, col=q*4+h4
        __half2 wh = __floats2half2_rn(wa, wb);
        uint2 d;
        d.x = (unsigned)(off + bse);
        d.y = *reinterpret_cast<unsigned*>(&wh);
        s_d[li] = d;
    }
    __syncthreads();

    // ---- Phase 2: gather + accumulate ----
    const int cb = tid >> 3;                 // LDS col = q*4+h4 [0,32)
    const int ls = tid & 7;                  // 16B slot within the 128B span
    const int h  = (hh << 2) | ((tid >> 3) & 3);

    float acc[8] = {0.f, 0.f, 0.f, 0.f, 0.f, 0.f, 0.f, 0.f};

    if (FP16) {
        const uint4* __restrict__ vb =
            (const uint4*)vh + (size_t)((b << 3) | h) * (NK * 4); // 4 uint4/key
        #pragma unroll 8
        for (int j = 0; j < 32; ++j) {
            const uint2 d = s_d[j * LDSS + cb];
            const __half2 wh = *reinterpret_cast<const __half2*>(&d.y);
            const float myw = (ls < 4) ? __low2float(wh) : __high2float(wh);
            const uint4 r = vb[(d.x << 2) + ls];   // rows base / base+1
            const float2 v0 = __half22float2(*(const __half2*)&r.x);
            const float2 v1 = __half22float2(*(const __half2*)&r.y);
            const float2 v2 = __half22float2(*(const __half2*)&r.z);
            const float2 v3 = __half22float2(*(const __half2*)&r.w);
            acc[0] += myw * v0.x;  acc[1] += myw * v0.y;
            acc[2] += myw * v1.x;  acc[3] += myw * v1.y;
            acc[4] += myw * v2.x;  acc[5] += myw * v2.y;
            acc[6] += myw * v3.x;  acc[7] += myw * v3.y;
        }
        // epilogue: fold row-(base+1) partials (lanes 4-7) into lanes 0-3
        #pragma unroll
        for (int i = 0; i < 8; ++i)
            acc[i] += __shfl_xor(acc[i], 4, 64);
        if (ls < 4) {
            float4* __restrict__ o4 = (float4*)out;
            const size_t orow = (size_t)(b * NQ + q0 + (cb >> 2)) * 64;
            o4[orow + (h << 3) + ls * 2]     = make_float4(acc[0], acc[1], acc[2], acc[3]);
            o4[orow + (h << 3) + ls * 2 + 1] = make_float4(acc[4], acc[5], acc[6], acc[7]);
        }
    } else {
        // fallback: original fp32 layout, two row loads, same encoding
        const float4* __restrict__ vb4 = (const float4*)value;
        #pragma unroll 8
        for (int j = 0; j < 32; ++j) {
            const uint2 d = s_d[j * LDSS + cb];
            const __half2 wh = *reinterpret_cast<const __half2*>(&d.y);
            const float wa = __low2float(wh);
            const float wb = __high2float(wh);
            const unsigned k2 = (d.x + 1 < NK) ? d.x + 1 : NK - 1;
            const size_t i1 = ((size_t)(b * NK) + d.x) * 64 + (h << 3) + ls;
            const size_t i2 = ((size_t)(b * NK) + k2)  * 64 + (h << 3) + ls;
            const float4 a = vb4[i1];
            const float4 c = vb4[i2];
            acc[0] += wa * a.x + wb * c.x;
            acc[1] += wa * a.y + wb * c.y;
            acc[2] += wa * a.z + wb * c.z;
            acc[3] += wa * a.w + wb * c.w;
        }
        float4* __restrict__ o4 = (float4*)out;
        o4[(size_t)(b * NQ + q0 + (cb >> 2)) * 64 + (h << 3) + ls] =
            make_float4(acc[0], acc[1], acc[2], acc[3]);
    }
}

extern "C" void kernel_launch(void* const* d_in, const int* in_sizes, int n_in,
                              void* d_out, int out_size, void* d_ws, size_t ws_size,
                              hipStream_t stream) {
    const float* value = (const float*)d_in[0];
    const float* loc   = (const float*)d_in[1];
    const float* wts   = (const float*)d_in[2];
    float* out = (float*)d_out;

    const int bs = 4;
    const int blocks = 8 * (NQ / 8);  // 8 groups x 512 = 4096
    const size_t need = (size_t)bs * NK * NH * ND * sizeof(__half) + 64; // +tail guard

    if (ws_size >= need) {
        cvt_t_kernel<<<bs * NH * 480, 256, 0, stream>>>(value, (uint4*)d_ws);
        spd_kernel<true><<<blocks, 256, 0, stream>>>(value, (const __half*)d_ws,
                                                     loc, wts, out);
    } else {
        spd_kernel<false><<<blocks, 256, 0, stream>>>(value, nullptr,
                                                      loc, wts, out);
    }
}

// Round 13
// 90.352 us; speedup vs baseline: 1.1520x; 1.0145x over previous
//
#include <hip/hip_runtime.h>
#include <hip/hip_fp16.h>

#define NQ 4096
#define NH 8
#define ND 32
#define NK 30720   // 16384+8192+4096+2048
#define LDSS 33    // padded LDS row stride (conflict-free)

typedef float f32x4 __attribute__((ext_vector_type(4)));

// ---- Pre-pass: value fp32 -> fp16 into workspace (halves gather traffic) ----
// Normal (temporal) stores: the vh lines written here warm L2/L3 for spd.
__global__ __launch_bounds__(256) void cvt_kernel(const float* __restrict__ v,
                                                  uint4* __restrict__ o, int n8) {
    int i = blockIdx.x * blockDim.x + threadIdx.x;
    const float4* __restrict__ v4 = (const float4*)v;
    for (; i < n8; i += gridDim.x * blockDim.x) {
        const float4 f0 = v4[2 * i];
        const float4 f1 = v4[2 * i + 1];
        __half2 h0 = __floats2half2_rn(f0.x, f0.y);
        __half2 h1 = __floats2half2_rn(f0.z, f0.w);
        __half2 h2 = __floats2half2_rn(f1.x, f1.y);
        __half2 h3 = __floats2half2_rn(f1.z, f1.w);
        uint4 u;
        u.x = *reinterpret_cast<unsigned*>(&h0);
        u.y = *reinterpret_cast<unsigned*>(&h1);
        u.z = *reinterpret_cast<unsigned*>(&h2);
        u.w = *reinterpret_cast<unsigned*>(&h3);
        o[i] = u;
    }
}

// Work partition (R5 winner, reverted verbatim): 8 groups = (batch, h-half),
// one per XCD; per-XCD distinct-line gather footprint 7.86 MB fp16 vs 4 MB L2
// -- the L2-capacity equilibrium sets the rate (7 scheduling/layout attacks
// all lost to this plain loop). Block: 8 queries x 4 heads.
// NEW vs R5: loc/wts loads and out stores are NON-TEMPORAL (evict-first) so
// the ~6 MB/XCD of streamed data doesn't evict gather lines from L2.
template <bool FP16>
__global__ __launch_bounds__(256, 8) void spd_kernel(
    const float* __restrict__ value,   // (bs, NK, H, D) fp32
    const __half* __restrict__ vh,     // same, fp16 (workspace), if FP16
    const float* __restrict__ loc,     // (bs, NQ, H, LV, P, 1)
    const float* __restrict__ wts,     // (bs, NQ, H, LV, P)
    float* __restrict__ out)           // (bs, NQ, H*D)
{
    const int tid = threadIdx.x;
    const int g  = blockIdx.x & 7;     // XCD id = group = b*2 + hh
    const int w  = blockIdx.x >> 3;    // [0,512) within group
    const int b  = g >> 1;
    const int hh = g & 1;              // which half of the 8 heads
    const int q0 = w << 3;             // first of 8 queries

    __shared__ uint2 s_d[32 * LDSS];   // [row=l*8+p][col=q*4+h4]

    // ---- Phase 1: descriptors for 8 queries x 4 heads x 32 taps ----
    const size_t base = ((size_t)(b * NQ + q0) * 8 + hh * 4) * 32;
    #pragma unroll
    for (int e = 0; e < 4; ++e) {
        const int ent = (e << 8) | tid;    // q(3b)|h4(2b)|l(2b)|p(3b)
        const size_t gidx = base + (size_t)(ent >> 7) * 256 + (ent & 127);
        const float x_loc = __builtin_nontemporal_load(&loc[gidx]);
        const float wq    = __builtin_nontemporal_load(&wts[gidx]);

        const int l   = (ent >> 3) & 3;
        const int L   = 16384 >> l;
        const int off = 32768 - (32768 >> l); // 0,16384,24576,28672

        const float x  = x_loc * (float)L - 1.0f;
        const float xf = floorf(x);
        const float lx = x - xf;
        const float hx = 1.0f - lx;
        const int   xl = (int)xf;
        const int   xh = xl + 1;

        const bool ok1 = (xl >= 0) && (xl < L);
        const bool ok2 = (xh >= 0) && (xh < L);
        int c1 = xl < 0 ? 0 : (xl > L - 1 ? L - 1 : xl);
        int c2 = xh < 0 ? 0 : (xh > L - 1 ? L - 1 : xh);
        const float w1 = ok1 ? wq * hx : 0.0f;
        const float w2 = ok2 ? wq * lx : 0.0f;

        const int li = (ent & 31) * LDSS + (ent >> 5);  // row=lp, col=q*4+h4
        __half2 wh = __floats2half2_rn(w1, w2);
        uint2 d;
        d.x = (unsigned)(off + c1) | ((unsigned)(off + c2) << 16);
        d.y = *reinterpret_cast<unsigned*>(&wh);
        s_d[li] = d;
    }
    __syncthreads();

    // ---- Phase 2: gather + accumulate (plain load-consume, proven) ----
    const int qi = tid >> 5;                 // query within block [0,8)
    const int cb = tid >> 3;                 // LDS col = q*4+h4 [0,32)
    const int h  = (hh << 2) | ((tid >> 3) & 3);
    const int d4 = tid & 7;
    const unsigned lane = (unsigned)((h << 3) | d4);  // slice within key row

    f32x4 acc = {0.f, 0.f, 0.f, 0.f};

    if (FP16) {
        const uint2* __restrict__ vb2 =
            (const uint2*)(vh) + (size_t)b * (NK * 64);   // 64 uint2 per key
        #pragma unroll 16
        for (int j = 0; j < 32; ++j) {
            const uint2 d = s_d[j * LDSS + cb];
            const __half2 wh = *reinterpret_cast<const __half2*>(&d.y);
            const float w1 = __low2float(wh);
            const float w2 = __high2float(wh);
            const uint2 r1 = vb2[((d.x & 0xffffu) << 6) + lane];
            const uint2 r2 = vb2[((d.x >> 16) << 6) + lane];
            const float2 a0 = __half22float2(*(const __half2*)&r1.x);
            const float2 a1 = __half22float2(*(const __half2*)&r1.y);
            const float2 c0 = __half22float2(*(const __half2*)&r2.x);
            const float2 c1 = __half22float2(*(const __half2*)&r2.y);
            acc.x += w1 * a0.x + w2 * c0.x;
            acc.y += w1 * a0.y + w2 * c0.y;
            acc.z += w1 * a1.x + w2 * c1.x;
            acc.w += w1 * a1.y + w2 * c1.y;
        }
    } else {
        const float4* __restrict__ vb4 =
            (const float4*)(value) + (size_t)b * (NK * 64); // 64 float4 per key
        #pragma unroll 16
        for (int j = 0; j < 32; ++j) {
            const uint2 d = s_d[j * LDSS + cb];
            const __half2 wh = *reinterpret_cast<const __half2*>(&d.y);
            const float w1 = __low2float(wh);
            const float w2 = __high2float(wh);
            const float4 a = vb4[(size_t)((d.x & 0xffffu) << 6) + lane];
            const float4 c = vb4[(size_t)((d.x >> 16) << 6) + lane];
            acc.x += w1 * a.x + w2 * c.x;
            acc.y += w1 * a.y + w2 * c.y;
            acc.z += w1 * a.z + w2 * c.z;
            acc.w += w1 * a.w + w2 * c.w;
        }
    }

    f32x4* __restrict__ o4 = (f32x4*)out;
    __builtin_nontemporal_store(acc, &o4[(size_t)(b * NQ + q0 + qi) * 64 + lane]);
}

extern "C" void kernel_launch(void* const* d_in, const int* in_sizes, int n_in,
                              void* d_out, int out_size, void* d_ws, size_t ws_size,
                              hipStream_t stream) {
    const float* value = (const float*)d_in[0];
    const float* loc   = (const float*)d_in[1];
    const float* wts   = (const float*)d_in[2];
    float* out = (float*)d_out;

    const int bs = 4;
    const int blocks = 8 * (NQ / 8);  // 8 groups x 512 = 4096
    const size_t need = (size_t)bs * NK * NH * ND * sizeof(__half);  // ~63 MB

    if (ws_size >= need) {
        const int n8 = bs * NK * NH * ND / 8;  // 8 floats per thread-iter
        cvt_kernel<<<2048, 256, 0, stream>>>(value, (uint4*)d_ws, n8);
        spd_kernel<true><<<blocks, 256, 0, stream>>>(value, (const __half*)d_ws,
                                                     loc, wts, out);
    } else {
        spd_kernel<false><<<blocks, 256, 0, stream>>>(value, nullptr,
                                                      loc, wts, out);
    }
}